// Round 5
// baseline (118.733 us; speedup 1.0000x reference)
//
#include <hip/hip_runtime.h>
#include <hip/hip_bf16.h>
#include <string.h>

#define N 4096
#define D 512
#define NB 32            // N/128 tile-rows; triangle blocks = NB*(NB+1)/2 = 528
#define NBLK (NB*(NB+1)/2)
#define BK 64
#define MARGIN 0.5f
#define FINF __builtin_huge_valf()

typedef __attribute__((ext_vector_type(8))) short bf16x8;   // 8 bf16 (4 VGPRs)
typedef __attribute__((ext_vector_type(4))) float f32x4;

__device__ inline float wave_sum(float v){
  #pragma unroll
  for (int off=32; off>0; off>>=1) v += __shfl_down(v, off, 64);
  return v;
}

// Pass 0: X (f32) -> bf16, row squared norms, init atomic arrays + ticket counter.
__global__ __launch_bounds__(128) void prep_kernel(const float* __restrict__ X,
    __hip_bfloat16* __restrict__ Xb, float* __restrict__ sq,
    unsigned int* __restrict__ hp2u, unsigned int* __restrict__ nm2u,
    unsigned int* __restrict__ counter){
  const int row = blockIdx.x;
  const int t = threadIdx.x;
  const float4 v = *(const float4*)(X + (size_t)row*D + t*4);
  ushort4 s;
  __hip_bfloat16 h;
  h = __float2bfloat16(v.x); memcpy(&s.x, &h, 2);
  h = __float2bfloat16(v.y); memcpy(&s.y, &h, 2);
  h = __float2bfloat16(v.z); memcpy(&s.z, &h, 2);
  h = __float2bfloat16(v.w); memcpy(&s.w, &h, 2);
  *(ushort4*)((unsigned short*)Xb + (size_t)row*D + t*4) = s;
  float ss = v.x*v.x + v.y*v.y + v.z*v.z + v.w*v.w;
  ss = wave_sum(ss);
  __shared__ float red[2];
  if ((t & 63) == 0) red[t >> 6] = ss;
  __syncthreads();
  if (t == 0){
    sq[row] = red[0] + red[1];
    hp2u[row] = 0u;                 // max-accumulator (d^2 domain, >= 0)
    nm2u[row] = 0x7F800000u;        // +inf: min-accumulator
    if (row == 0) counter[0] = 0u;
  }
}

// Fused triangle GEMM + hardest-pos/neg reductions + last-block final reduce.
// Single-barrier double-buffered K-loop (BK=64), XOR-swizzled LDS layout so the
// global_load_lds (wave-uniform base + lane*16) layout is bank-conflict-free on
// the 128B-row-stride fragment reads.
__global__ __launch_bounds__(256,1) void gemm_fused(const __hip_bfloat16* __restrict__ Xb,
    const float* __restrict__ sq, const int* __restrict__ lab,
    unsigned int* __restrict__ hp2u, unsigned int* __restrict__ nm2u,
    unsigned int* __restrict__ counter, float* __restrict__ out){
  __shared__ __align__(16) __hip_bfloat16 As[2][128*BK];   // 32 KB
  __shared__ __align__(16) __hip_bfloat16 Bs[2][128*BK];   // 32 KB
  __shared__ float sqi[128];
  __shared__ float sqj[128];
  __shared__ int labi_s[128];
  __shared__ int labj_s[128];
  __shared__ unsigned int tick;

  // linear block -> (bi, bj) with bi <= bj
  int rem = blockIdx.x, bi = 0;
  while (rem >= NB - bi){ rem -= NB - bi; bi++; }
  const int bj = bi + rem;
  const int row0 = bi * 128, col0 = bj * 128;

  const int tid = threadIdx.x;
  const int wave = tid >> 6, lane = tid & 63;
  const int wr = (wave >> 1) * 64, wc = (wave & 1) * 64;
  if (tid < 128) {
    sqi[tid] = sq[row0 + tid]; sqj[tid] = sq[col0 + tid];
    labi_s[tid] = lab[row0 + tid]; labj_s[tid] = lab[col0 + tid];
  }

  // Staging geometry: per call, 64 lanes cover 8 rows x 8 chunks (16B each).
  // LDS slot (row, s) holds global chunk g = s ^ (row&7)  [row&7 == lane>>3].
  const int srg = lane >> 3;                 // row within 8-row group, 0..7
  const int gchunk = (lane & 7) ^ srg;       // swizzled global chunk for this lane

  auto stage = [&](int buf, int k0){
    #pragma unroll
    for (int c = 0; c < 4; ++c){
      const int rgrp = wave*32 + c*8;        // wave-uniform row-group base
      const __hip_bfloat16* ga = Xb + (size_t)(row0 + rgrp + srg)*D + k0 + gchunk*8;
      const __hip_bfloat16* gb = Xb + (size_t)(col0 + rgrp + srg)*D + k0 + gchunk*8;
      __builtin_amdgcn_global_load_lds((const __attribute__((address_space(1))) void*)ga,
          (__attribute__((address_space(3))) void*)(&As[buf][rgrp*BK]), 16, 0, 0);
      __builtin_amdgcn_global_load_lds((const __attribute__((address_space(1))) void*)gb,
          (__attribute__((address_space(3))) void*)(&Bs[buf][rgrp*BK]), 16, 0, 0);
    }
  };

  f32x4 acc[4][4];
  #pragma unroll
  for (int a=0;a<4;a++)
    #pragma unroll
    for (int b=0;b<4;b++)
      acc[a][b] = (f32x4){0.f,0.f,0.f,0.f};

  const int fr = lane & 15, q = lane >> 4;
  const int fslot_base = fr & 7;             // slot = g ^ (row&7), row&7 == fr&7

  stage(0, 0);
  for (int it = 0; it < D/BK; ++it){
    __syncthreads();                          // drains vmcnt -> buf[it&1] ready
    if (it + 1 < D/BK) stage((it+1)&1, (it+1)*BK);   // prefetch overlaps compute
    const __hip_bfloat16* Ab = &As[it&1][0];
    const __hip_bfloat16* Bb = &Bs[it&1][0];
    #pragma unroll
    for (int half = 0; half < 2; ++half){     // kk = 0, 32
      const int g = q + half*4;               // k-chunk index 0..7
      const int slot = g ^ fslot_base;
      bf16x8 af[4], bfr[4];
      #pragma unroll
      for (int a=0;a<4;a++){
        af[a]  = *(const bf16x8*)(Ab + (wr + a*16 + fr)*BK + slot*8);
        bfr[a] = *(const bf16x8*)(Bb + (wc + a*16 + fr)*BK + slot*8);
      }
      #pragma unroll
      for (int a=0;a<4;a++)
        #pragma unroll
        for (int b=0;b<4;b++)
          acc[a][b] = __builtin_amdgcn_mfma_f32_16x16x32_bf16(af[a], bfr[b], acc[a][b], 0, 0, 0);
    }
  }

  // Epilogue. C/D layout: col=lane&15, row=(lane>>4)*4+v (m89-verified).
  const int colq = lane & 15, g4 = lane >> 4, rowq = g4 * 4;
  int   labi_r[16]; float sqi_r[16];
  #pragma unroll
  for (int a=0;a<4;a++)
    #pragma unroll
    for (int v=0;v<4;v++){
      const int iloc = wr + a*16 + rowq + v;
      labi_r[a*4+v] = labi_s[iloc];
      sqi_r[a*4+v]  = sqi[iloc];
    }

  float pmax_r[16], nmin_r[16];
  #pragma unroll
  for (int k=0;k<16;k++){ pmax_r[k] = 0.f; nmin_r[k] = FINF; }
  float cpos[4], cmin[4];

  #pragma unroll
  for (int b=0;b<4;b++){
    const int jloc = wc + b*16 + colq;
    const float sj = sqj[jloc];
    const int lj = labj_s[jloc];
    float cp = 0.f, cn = FINF;
    #pragma unroll
    for (int a=0;a<4;a++)
      #pragma unroll
      for (int v=0;v<4;v++){
        const int k = a*4+v;
        const float d2 = fmaf(acc[a][b][v], -2.0f, sqi_r[k] + sj);
        const bool same = (labi_r[k] == lj);         // covers diag (i==j)
        const float sp = same ? d2 : 0.0f;           // positive candidate
        const float sn = same ? FINF : d2;           // negative candidate
        pmax_r[k] = fmaxf(pmax_r[k], sp);
        nmin_r[k] = fminf(nmin_r[k], sn);
        cp = fmaxf(cp, sp);
        cn = fminf(cn, sn);
      }
    cpos[b] = cp; cmin[b] = cn;
  }

  // Row-direction: reduce across the 16 lanes sharing a row (xor stays in-group).
  #pragma unroll
  for (int k=0;k<16;k++){
    float p = pmax_r[k], n = nmin_r[k];
    #pragma unroll
    for (int m=1;m<16;m<<=1){
      p = fmaxf(p, __shfl_xor(p, m, 64));
      n = fminf(n, __shfl_xor(n, m, 64));
    }
    if (colq == 0){
      const int ig = row0 + wr + (k>>2)*16 + rowq + (k&3);
      atomicMax(hp2u + ig, __float_as_uint(p));                 // p >= 0
      atomicMin(nm2u + ig, __float_as_uint(fmaxf(n, 0.f)));     // clamp: monotone
    }
  }
  // Column-direction (symmetry): reduce across the 4 lane-groups.
  #pragma unroll
  for (int b=0;b<4;b++){
    float p = cpos[b], n = cmin[b];
    p = fmaxf(p, __shfl_xor(p, 16, 64)); p = fmaxf(p, __shfl_xor(p, 32, 64));
    n = fminf(n, __shfl_xor(n, 16, 64)); n = fminf(n, __shfl_xor(n, 32, 64));
    if (g4 == 0){
      const int jg = col0 + wc + b*16 + colq;
      atomicMax(hp2u + jg, __float_as_uint(p));
      atomicMin(nm2u + jg, __float_as_uint(fmaxf(n, 0.f)));
    }
  }

  // Last-block final reduction (replaces a separate kernel launch).
  __threadfence();
  __syncthreads();
  if (tid == 0) tick = atomicAdd(counter, 1u);
  __syncthreads();
  if (tick == NBLK - 1){
    float s = 0.f;
    #pragma unroll
    for (int itr = 0; itr < 16; ++itr){
      const int i = tid + itr * 256;
      // non-destructive device-scope atomic reads (max(x,0)=x for our domains)
      const float hp2 = __uint_as_float(atomicMax(hp2u + i, 0u));
      const float nm2 = __uint_as_float(atomicMax(nm2u + i, 0u));
      s += sqrtf(hp2 + 1e-12f) + fmaxf(MARGIN - sqrtf(nm2 + 1e-12f), 0.f);
    }
    s = wave_sum(s);
    if ((tid & 63) == 0) sqi[tid >> 6] = s;   // reuse LDS as scratch
    __syncthreads();
    if (tid == 0) out[0] = (sqi[0] + sqi[1] + sqi[2] + sqi[3]) * (1.0f / (float)N);
  }
}

extern "C" void kernel_launch(void* const* d_in, const int* in_sizes, int n_in,
                              void* d_out, int out_size, void* d_ws, size_t ws_size,
                              hipStream_t stream) {
  (void)in_sizes; (void)n_in; (void)out_size; (void)ws_size;
  const float* X  = (const float*)d_in[0];
  const int* lab  = (const int*)d_in[1];
  float* out      = (float*)d_out;

  char* ws = (char*)d_ws;
  __hip_bfloat16* Xb    = (__hip_bfloat16*)ws;                 // 4 MB
  float* sq             = (float*)(Xb + (size_t)N * D);        // 16 KB
  unsigned int* hp2u    = (unsigned int*)(sq + N);             // 16 KB
  unsigned int* nm2u    = hp2u + N;                            // 16 KB
  unsigned int* counter = nm2u + N;                            // 4 B

  prep_kernel<<<N, 128, 0, stream>>>(X, Xb, sq, hp2u, nm2u, counter);
  gemm_fused<<<NBLK, 256, 0, stream>>>(Xb, sq, lab, hp2u, nm2u, counter, out);
}